// Round 3
// baseline (269.235 us; speedup 1.0000x reference)
//
#include <hip/hip_runtime.h>

#define B 8
#define C 512
#define D 2048   // spatial positions
#define L 2049   // D+1
#define NH 8
#define CH 64
#define NB 256   // grid blocks (persistent)
#define NT 512   // threads per block (8 waves)

__device__ __forceinline__ float wave_sum(float v) {
  #pragma unroll
  for (int off = 32; off; off >>= 1) v += __shfl_down(v, off);
  return v;
}
__device__ __forceinline__ float wave_max(float v) {
  #pragma unroll
  for (int off = 32; off; off >>= 1) v = fmaxf(v, __shfl_down(v, off));
  return v;
}

// Grid barrier: per-block arrival slots (no contention) + master-block release
// flag. Monotone phase values; slots/flag zeroed by hipMemsetAsync each launch.
// All 256 blocks are resident by construction (256 blocks <= 1/CU x 256 CUs
// even at worst-case VGPR/LDS), so spinning is deadlock-free.
__device__ __forceinline__ void grid_barrier(unsigned* slots, unsigned* flag,
                                             unsigned phase, int bid, int tid) {
  __syncthreads();  // drains vmcnt per wave -> block's writes are in L2
  if (tid == 0)
    __hip_atomic_store(&slots[bid], phase, __ATOMIC_RELEASE, __HIP_MEMORY_SCOPE_AGENT);
  if (bid == 0) {
    if (tid < NB)
      while (__hip_atomic_load(&slots[tid], __ATOMIC_ACQUIRE, __HIP_MEMORY_SCOPE_AGENT) < phase)
        __builtin_amdgcn_s_sleep(2);
    __syncthreads();
    if (tid == 0)
      __hip_atomic_store(flag, phase, __ATOMIC_RELEASE, __HIP_MEMORY_SCOPE_AGENT);
  } else if (tid == 0) {
    while (__hip_atomic_load(flag, __ATOMIC_ACQUIRE, __HIP_MEMORY_SCOPE_AGENT) < phase)
      __builtin_amdgcn_s_sleep(2);
  }
  __syncthreads();
}

__global__ void __launch_bounds__(NT) k_fused(
    const float* __restrict__ x, const float* __restrict__ pos,
    const float* __restrict__ wqkv, const float* __restrict__ bqkv,
    const float* __restrict__ wc, const float* __restrict__ bc,
    float* __restrict__ out,
    unsigned* slots, unsigned* flag,
    float* mean, float* u, float* logit0, float* wpart, float* xbar, float* a0v) {

  __shared__ union {
    struct { float mps[C]; float q0s[CH]; float us[C]; float red[8]; } p2;
    struct { float ulds[NH][C]; float rlds[8][NH][128]; } p3;
    struct { float w[NH][D]; float w0e[NH]; float sinv[NH]; } p4;
    struct { float row[C]; } p56;
  } sm;

  const int bid = blockIdx.x, tid = threadIdx.x;
  const int wid = tid >> 6, lane = tid & 63;

  // ---- P1: mean over D per (b,c) row. 16 rows/block, 2 rows/wave. ----
  {
    #pragma unroll
    for (int r = 0; r < 2; ++r) {
      int row = bid * 16 + wid * 2 + r;
      const float4* xr = reinterpret_cast<const float4*>(x + (size_t)row * D);
      float s = 0.f;
      #pragma unroll
      for (int k = 0; k < 8; ++k) { float4 v = xr[lane + k * 64]; s += (v.x + v.y) + (v.z + v.w); }
      s = wave_sum(s);
      if (lane == 0) mean[row] = s * (1.0f / D);
    }
  }
  grid_barrier(slots, flag, 1u, bid, tid);

  // ---- P2: q0 -> u -> logit0 per (b,h). 64 active blocks. ----
  if (bid < B * NH) {
    int b = bid >> 3, h = bid & 7;
    sm.p2.mps[tid] = mean[b * C + tid] + pos[(size_t)tid * L];
    __syncthreads();
    for (int j = wid; j < CH; j += 8) {
      const float* wr = wqkv + (size_t)(h * CH + j) * C;
      float acc = 0.f;
      #pragma unroll
      for (int k = 0; k < 8; ++k) acc += wr[lane + k * 64] * sm.p2.mps[lane + k * 64];
      acc = wave_sum(acc);
      if (lane == 0) sm.p2.q0s[j] = acc + bqkv[h * CH + j];
    }
    __syncthreads();
    {
      float a = 0.f;
      #pragma unroll 4
      for (int j = 0; j < CH; ++j)
        a += sm.p2.q0s[j] * wqkv[(size_t)(C + h * CH + j) * C + tid];
      a *= 0.125f;  // scale^2 = 1/sqrt(64)
      sm.p2.us[tid] = a;
      u[(size_t)bid * C + tid] = a;
    }
    __syncthreads();
    {
      float p = sm.p2.us[tid] * sm.p2.mps[tid];
      p = wave_sum(p);
      if (lane == 0) sm.p2.red[wid] = p;
      __syncthreads();
      if (tid == 0) {
        float s = 0.f;
        #pragma unroll
        for (int w = 0; w < 8; ++w) s += sm.p2.red[w];
        logit0[bid] = s;
      }
    }
  }
  grid_barrier(slots, flag, 2u, bid, tid);

  // ---- P3: logits[b,h,l], l>=1. 128 active blocks = 8 b x 16 l-tiles.
  //      Block covers all 512 c (8 waves x 64 c), 128 l per block. ----
  if (bid < 128) {
    int b = bid >> 4, lt = bid & 15;
    for (int idx = tid; idx < NH * C; idx += NT) {
      int h = idx >> 9, c = idx & 511;
      sm.p3.ulds[h][c] = u[(size_t)(b * NH + h) * C + c];
    }
    __syncthreads();
    int l0 = lt * 128 + lane * 2;          // x column; actual l = l0+1
    int cg = wid * 64;
    const float* xp = x + ((size_t)(b * C + cg)) * D + l0;
    const float* pp = pos + (size_t)cg * L + l0 + 1;
    float2 acc[NH];
    #pragma unroll
    for (int h = 0; h < NH; ++h) acc[h] = make_float2(0.f, 0.f);
    #pragma unroll 4
    for (int cc = 0; cc < 64; ++cc) {
      float2 xv = *reinterpret_cast<const float2*>(xp);
      float v0 = xv.x + pp[0];
      float v1 = xv.y + pp[1];
      #pragma unroll
      for (int h = 0; h < NH; ++h) {
        float uu = sm.p3.ulds[h][cg + cc];
        acc[h].x += uu * v0;
        acc[h].y += uu * v1;
      }
      xp += D; pp += L;
    }
    #pragma unroll
    for (int h = 0; h < NH; ++h) {
      sm.p3.rlds[wid][h][lane * 2]     = acc[h].x;
      sm.p3.rlds[wid][h][lane * 2 + 1] = acc[h].y;
    }
    __syncthreads();
    for (int idx = tid; idx < NH * 128; idx += NT) {
      int h = idx >> 7, ll = idx & 127;
      float s = 0.f;
      #pragma unroll
      for (int w = 0; w < 8; ++w) s += sm.p3.rlds[w][h][ll];
      wpart[(size_t)(b * NH + h) * D + lt * 128 + ll] = s;
    }
  }
  grid_barrier(slots, flag, 3u, bid, tid);

  // ---- P4: per-block softmax rebuild (8 rows in LDS) + xbar for 16 c. ----
  {
    int b = bid >> 5, c0 = (bid & 31) * 16;
    {
      int h = wid;  // one head row per wave
      const float* p0 = wpart + (size_t)(b * NH + h) * D;
      float lg0 = logit0[b * NH + h];
      float m = lg0;
      #pragma unroll
      for (int k = 0; k < 8; ++k) {
        int li = (k * 64 + lane) * 4;
        float4 v = *reinterpret_cast<const float4*>(&p0[li]);
        *reinterpret_cast<float4*>(&sm.p4.w[h][li]) = v;
        m = fmaxf(m, fmaxf(fmaxf(v.x, v.y), fmaxf(v.z, v.w)));
      }
      m = wave_max(m);
      m = __shfl(m, 0);
      float s = 0.f;
      #pragma unroll
      for (int k = 0; k < 8; ++k) {
        int li = (k * 64 + lane) * 4;
        float4 v = *reinterpret_cast<const float4*>(&sm.p4.w[h][li]);
        v.x = __expf(v.x - m); v.y = __expf(v.y - m);
        v.z = __expf(v.z - m); v.w = __expf(v.w - m);
        *reinterpret_cast<float4*>(&sm.p4.w[h][li]) = v;
        s += (v.x + v.y) + (v.z + v.w);
      }
      s = wave_sum(s);
      if (lane == 0) {
        float e0 = __expf(lg0 - m);
        sm.p4.w0e[h] = e0;
        sm.p4.sinv[h] = 1.0f / (s + e0);
      }
    }
    __syncthreads();
    // dots: wave handles 2 c
    float acc[2][NH];
    #pragma unroll
    for (int cc = 0; cc < 2; ++cc)
      #pragma unroll
      for (int h = 0; h < NH; ++h) acc[cc][h] = 0.f;
    int cbase = c0 + wid * 2;
    #pragma unroll 2
    for (int k = 0; k < 8; ++k) {
      int li = (k * 64 + lane) * 4;
      float4 wv[NH];
      #pragma unroll
      for (int h = 0; h < NH; ++h) wv[h] = *reinterpret_cast<const float4*>(&sm.p4.w[h][li]);
      #pragma unroll
      for (int cc = 0; cc < 2; ++cc) {
        int c = cbase + cc;
        float4 xv = *reinterpret_cast<const float4*>(x + (size_t)(b * C + c) * D + li);
        const float* pp = pos + (size_t)c * L + 1 + li;
        float v0 = xv.x + pp[0], v1 = xv.y + pp[1], v2 = xv.z + pp[2], v3 = xv.w + pp[3];
        #pragma unroll
        for (int h = 0; h < NH; ++h)
          acc[cc][h] += wv[h].x * v0 + wv[h].y * v1 + wv[h].z * v2 + wv[h].w * v3;
      }
    }
    #pragma unroll
    for (int cc = 0; cc < 2; ++cc) {
      int c = cbase + cc;
      float x0 = mean[b * C + c] + pos[(size_t)c * L];
      #pragma unroll
      for (int h = 0; h < NH; ++h) {
        float a = wave_sum(acc[cc][h]);
        if (lane == 0)
          xbar[(size_t)(b * NH + h) * C + c] = (a + sm.p4.w0e[h] * x0) * sm.p4.sinv[h];
      }
    }
  }
  grid_barrier(slots, flag, 4u, bid, tid);

  // ---- P5: a0[b,cv] = W_v[cv,:].xbar[b,h(cv),:] + b_v[cv]. 64 active blocks. ----
  if (bid < B * NH) {
    int b = bid >> 3, h = bid & 7;
    for (int c = tid; c < C; c += NT) sm.p56.row[c] = xbar[(size_t)(b * NH + h) * C + c];
    __syncthreads();
    #pragma unroll 2
    for (int j = 0; j < 8; ++j) {
      int o = h * CH + wid * 8 + j;   // cv in [64h, 64h+64)
      const float* wr = wqkv + (size_t)(2 * C + o) * C;
      float acc = 0.f;
      #pragma unroll
      for (int k = 0; k < 8; ++k) acc += wr[lane + k * 64] * sm.p56.row[lane + k * 64];
      acc = wave_sum(acc);
      if (lane == 0) a0v[b * C + o] = acc + bqkv[2 * C + o];
    }
  }
  grid_barrier(slots, flag, 5u, bid, tid);

  // ---- P6: out[b,o] = W_c[o,:].a0[b,:] + b_c[o]. 64 active blocks. ----
  if (bid < B * NH) {
    int b = bid >> 3, oc = (bid & 7) * 64;
    for (int c = tid; c < C; c += NT) sm.p56.row[c] = a0v[b * C + c];
    __syncthreads();
    #pragma unroll 2
    for (int j = 0; j < 8; ++j) {
      int o = oc + wid * 8 + j;
      const float* wr = wc + (size_t)o * C;
      float acc = 0.f;
      #pragma unroll
      for (int k = 0; k < 8; ++k) acc += wr[lane + k * 64] * sm.p56.row[lane + k * 64];
      acc = wave_sum(acc);
      if (lane == 0) out[b * C + o] = acc + bc[o];
    }
  }
}

extern "C" void kernel_launch(void* const* d_in, const int* in_sizes, int n_in,
                              void* d_out, int out_size, void* d_ws, size_t ws_size,
                              hipStream_t stream) {
  const float* x    = (const float*)d_in[0];
  const float* pos  = (const float*)d_in[1];
  const float* wqkv = (const float*)d_in[2];
  const float* bqkv = (const float*)d_in[3];
  const float* wc   = (const float*)d_in[4];
  const float* bc   = (const float*)d_in[5];
  float* out = (float*)d_out;
  float* ws  = (float*)d_ws;

  unsigned* slots = (unsigned*)ws;        // [0..255]
  unsigned* flag  = (unsigned*)ws + 256;  // [256]
  float* mean   = ws + 1024;    // 4096
  float* u      = ws + 5120;    // 32768
  float* logit0 = ws + 37888;   // 64
  float* wpart  = ws + 37952;   // 64*2048 = 131072
  float* xbar   = ws + 169024;  // 32768
  float* a0v    = ws + 201792;  // 4096  -> total ~824 KB

  hipMemsetAsync(ws, 0, 4096, stream);  // zero barrier slots+flag each launch
  hipLaunchKernelGGL(k_fused, dim3(NB), dim3(NT), 0, stream,
                     x, pos, wqkv, bqkv, wc, bc, out,
                     slots, flag, mean, u, logit0, wpart, xbar, a0v);
}

// Round 4
// 62.818 us; speedup vs baseline: 4.2859x; 4.2859x over previous
//
#include <hip/hip_runtime.h>

#define B 8
#define C 512
#define D 2048     // spatial positions
#define L 2049     // D+1
#define NH 8
#define CH 64
#define NLT 32     // l-tiles of 64 in the fused pass
#define TLD 513    // LDS tile leading dim (conflict-free odd stride)

__device__ __forceinline__ float wave_sum(float v) {
  #pragma unroll
  for (int off = 32; off; off >>= 1) v += __shfl_down(v, off);
  return v;
}
__device__ __forceinline__ float wave_max(float v) {
  #pragma unroll
  for (int off = 32; off; off >>= 1) v = fmaxf(v, __shfl_down(v, off));
  return v;
}

// ---- K1: mean over D per (b,c) row. One block per row. ----
__global__ void __launch_bounds__(256) k_mean(const float* __restrict__ x, float* __restrict__ mean) {
  int row = blockIdx.x;  // b*C + c
  const float4* xr = reinterpret_cast<const float4*>(x + (size_t)row * D);
  float s = 0.f;
  #pragma unroll
  for (int i = 0; i < 2; ++i) {
    float4 v = xr[threadIdx.x + i * 256];
    s += (v.x + v.y) + (v.z + v.w);
  }
  __shared__ float red[4];
  s = wave_sum(s);
  if ((threadIdx.x & 63) == 0) red[threadIdx.x >> 6] = s;
  __syncthreads();
  if (threadIdx.x == 0) mean[row] = (red[0] + red[1] + red[2] + red[3]) * (1.0f / D);
}

// ---- K2: q0 -> u[b,h,:] -> logit0[b,h]. One block per (b,h). ----
// (k-bias term is constant over l -> softmax-invariant -> dropped.)
__global__ void __launch_bounds__(256) k_qu(const float* __restrict__ wqkv,
                                            const float* __restrict__ bqkv,
                                            const float* __restrict__ pos,
                                            const float* __restrict__ mean,
                                            float* __restrict__ u,
                                            float* __restrict__ logit0) {
  int bh = blockIdx.x, b = bh >> 3, h = bh & 7;
  int tid = threadIdx.x, wid = tid >> 6, lane = tid & 63;
  __shared__ float mps[C];
  __shared__ float q0s[CH];
  __shared__ float us[C];
  __shared__ float red[4];
  for (int c = tid; c < C; c += 256) mps[c] = mean[b * C + c] + pos[(size_t)c * L];
  __syncthreads();
  for (int j = wid; j < CH; j += 4) {
    const float* wr = wqkv + (size_t)(h * CH + j) * C;
    float acc = 0.f;
    #pragma unroll
    for (int k = 0; k < 8; ++k) acc += wr[lane + k * 64] * mps[lane + k * 64];
    acc = wave_sum(acc);
    if (lane == 0) q0s[j] = acc + bqkv[h * CH + j];
  }
  __syncthreads();
  float a0 = 0.f, a1 = 0.f;
  #pragma unroll 4
  for (int j = 0; j < CH; ++j) {
    float qv = q0s[j];
    const float* wkr = wqkv + (size_t)(C + h * CH + j) * C;
    a0 += qv * wkr[tid];
    a1 += qv * wkr[tid + 256];
  }
  a0 *= 0.125f; a1 *= 0.125f;   // scale^2 = 1/sqrt(64)
  us[tid] = a0; us[tid + 256] = a1;
  u[(size_t)bh * C + tid] = a0;
  u[(size_t)bh * C + tid + 256] = a1;
  __syncthreads();
  float p = us[tid] * mps[tid] + us[tid + 256] * mps[tid + 256];
  p = wave_sum(p);
  if (lane == 0) red[wid] = p;
  __syncthreads();
  if (tid == 0) logit0[bh] = red[0] + red[1] + red[2] + red[3];
}

// ---- K3: fused logits + local softmax + xbar partials. ----
// grid (NLT, B), 512 thr. Block stages its 512c x 64l x+pos tile in LDS,
// computes logits (lane<->l, wave<->64c chunk, u in regs + shfl broadcast),
// local softmax over its 64 l's, then accumulates sum_l e*xf (thread<->c)
// from the LDS tile. x read once from L3; tile re-read is LDS.
__global__ void __launch_bounds__(512, 1) k_fused_lx(
    const float* __restrict__ x, const float* __restrict__ pos,
    const float* __restrict__ u_g,
    float* __restrict__ xpart, float* __restrict__ mpart, float* __restrict__ spart) {
  __shared__ float tile[64][TLD];     // 131328 B
  __shared__ float rlds[8][NH][64];   // 16384 B
  __shared__ float e_lds[NH][64];     // 2048 B   (total ~149.8 KB)
  int lt = blockIdx.x, b = blockIdx.y;
  int tid = threadIdx.x, wid = tid >> 6, lane = tid & 63;
  int cg = wid * 64;
  int col = lt * 64 + lane;           // x column; actual l = col+1

  float ureg[NH];
  #pragma unroll
  for (int h = 0; h < NH; ++h) ureg[h] = u_g[(size_t)(b * NH + h) * C + cg + lane];

  float acc[NH];
  #pragma unroll
  for (int h = 0; h < NH; ++h) acc[h] = 0.f;

  const float* xp = x + ((size_t)(b * C + cg)) * D + col;
  const float* pp = pos + (size_t)cg * L + col + 1;
  #pragma unroll 4
  for (int cc = 0; cc < 64; ++cc) {
    float v = *xp + *pp;
    tile[lane][cg + cc] = v;
    xp += D; pp += L;
    #pragma unroll
    for (int h = 0; h < NH; ++h) acc[h] += __shfl(ureg[h], cc) * v;
  }
  #pragma unroll
  for (int h = 0; h < NH; ++h) rlds[wid][h][lane] = acc[h];
  __syncthreads();

  {  // wave wid finishes head h = wid: reduce over waves, local softmax
    int h = wid;
    float lg = 0.f;
    #pragma unroll
    for (int w = 0; w < 8; ++w) lg += rlds[w][h][lane];
    float m = wave_max(lg);
    m = __shfl(m, 0);
    float e = __expf(lg - m);
    float s = wave_sum(e);
    e_lds[h][lane] = e;
    if (lane == 0) {
      mpart[(b * NH + h) * NLT + lt] = m;
      spart[(b * NH + h) * NLT + lt] = s;
    }
  }
  __syncthreads();

  // xbar partial: thread <-> c, loop the block's 64 l's from LDS
  float a2[NH];
  #pragma unroll
  for (int h = 0; h < NH; ++h) a2[h] = 0.f;
  #pragma unroll 4
  for (int l = 0; l < 64; ++l) {
    float xv = tile[l][tid];
    #pragma unroll
    for (int h = 0; h < NH; ++h) a2[h] += e_lds[h][l] * xv;
  }
  #pragma unroll
  for (int h = 0; h < NH; ++h)
    xpart[(((size_t)b * NLT + lt) * NH + h) * C + tid] = a2[h];
}

// ---- K4: combine 32 tile-partials (rescale by global max) + l=0 term,
//          normalize -> xbar row, then a0 slice for this head. Block = (b,h). ----
__global__ void __launch_bounds__(512) k_comb_a0(
    const float* __restrict__ xpart, const float* __restrict__ mpart,
    const float* __restrict__ spart, const float* __restrict__ logit0,
    const float* __restrict__ mean, const float* __restrict__ pos,
    const float* __restrict__ wqkv, const float* __restrict__ bqkv,
    float* __restrict__ a0v) {
  int bh = blockIdx.x, b = bh >> 3, h = bh & 7;
  int tid = threadIdx.x, wid = tid >> 6, lane = tid & 63;
  __shared__ float row[C];
  __shared__ float rr[NLT];
  __shared__ float Msh, Sinv;
  float lg0 = logit0[bh];
  if (tid < NLT) rr[tid] = mpart[bh * NLT + tid];
  __syncthreads();
  if (tid == 0) {
    float M = lg0;
    #pragma unroll
    for (int t = 0; t < NLT; ++t) M = fmaxf(M, rr[t]);
    Msh = M;
  }
  __syncthreads();
  float M = Msh;
  if (tid < NLT) rr[tid] = __expf(rr[tid] - M);
  __syncthreads();
  if (tid == 0) {
    float S = __expf(lg0 - M);
    #pragma unroll
    for (int t = 0; t < NLT; ++t) S += spart[bh * NLT + t] * rr[t];
    Sinv = 1.0f / S;
  }
  float acc = 0.f;
  #pragma unroll 4
  for (int t = 0; t < NLT; ++t)
    acc += xpart[(((size_t)b * NLT + t) * NH + h) * C + tid] * rr[t];
  float xf0 = mean[b * C + tid] + pos[(size_t)tid * L];
  acc += __expf(lg0 - M) * xf0;
  __syncthreads();               // Sinv ready
  row[tid] = acc * Sinv;
  __syncthreads();
  // a0[b, h*64+j] = W_v[h*64+j,:] . row + b_v
  #pragma unroll 2
  for (int j = 0; j < 8; ++j) {
    int o = h * CH + wid * 8 + j;
    const float* wr = wqkv + (size_t)(2 * C + o) * C;
    float d = 0.f;
    #pragma unroll
    for (int k = 0; k < 8; ++k) d += wr[lane + k * 64] * row[lane + k * 64];
    d = wave_sum(d);
    if (lane == 0) a0v[b * C + o] = d + bqkv[2 * C + o];
  }
}

// ---- K5: out[b,o] = W_c[o,:] . a0[b,:] + b_c[o]. Block = (b, 64-o chunk). ----
__global__ void __launch_bounds__(512) k_out(const float* __restrict__ wc,
                                             const float* __restrict__ bc,
                                             const float* __restrict__ a0v,
                                             float* __restrict__ out) {
  int bid = blockIdx.x, b = bid >> 3, og = (bid & 7) * 64;
  int tid = threadIdx.x, wid = tid >> 6, lane = tid & 63;
  __shared__ float row[C];
  row[tid] = a0v[b * C + tid];
  __syncthreads();
  #pragma unroll 2
  for (int j = 0; j < 8; ++j) {
    int o = og + wid * 8 + j;
    const float* wr = wc + (size_t)o * C;
    float d = 0.f;
    #pragma unroll
    for (int k = 0; k < 8; ++k) d += wr[lane + k * 64] * row[lane + k * 64];
    d = wave_sum(d);
    if (lane == 0) out[b * C + o] = d + bc[o];
  }
}

extern "C" void kernel_launch(void* const* d_in, const int* in_sizes, int n_in,
                              void* d_out, int out_size, void* d_ws, size_t ws_size,
                              hipStream_t stream) {
  const float* x    = (const float*)d_in[0];
  const float* pos  = (const float*)d_in[1];
  const float* wqkv = (const float*)d_in[2];
  const float* bqkv = (const float*)d_in[3];
  const float* wc   = (const float*)d_in[4];
  const float* bc   = (const float*)d_in[5];
  float* out = (float*)d_out;
  float* ws  = (float*)d_ws;

  float* mean   = ws;               // 4096
  float* u      = ws + 4096;        // 32768
  float* logit0 = ws + 36864;       // 64
  float* mpart  = ws + 36928;       // 2048
  float* spart  = ws + 38976;       // 2048
  float* a0v    = ws + 41024;       // 4096
  float* xpart  = ws + 45120;       // 8*32*8*512 = 1048576  (total ~4.4 MB)

  hipLaunchKernelGGL(k_mean,     dim3(B * C),    dim3(256), 0, stream, x, mean);
  hipLaunchKernelGGL(k_qu,       dim3(B * NH),   dim3(256), 0, stream, wqkv, bqkv, pos, mean, u, logit0);
  hipLaunchKernelGGL(k_fused_lx, dim3(NLT, B),   dim3(512), 0, stream, x, pos, u, xpart, mpart, spart);
  hipLaunchKernelGGL(k_comb_a0,  dim3(B * NH),   dim3(512), 0, stream, xpart, mpart, spart, logit0,
                     mean, pos, wqkv, bqkv, a0v);
  hipLaunchKernelGGL(k_out,      dim3(B * NH),   dim3(512), 0, stream, wc, bc, a0v, out);
}

// Round 5
// 58.095 us; speedup vs baseline: 4.6344x; 1.0813x over previous
//
#include <hip/hip_runtime.h>

#define B 8
#define C 512
#define D 2048     // spatial positions
#define L 2049     // D+1
#define NH 8
#define CH 64
#define NLT 32     // l-tiles of 64 in the fused pass
#define TLD 513    // LDS tile leading dim (odd stride -> 2-way/free on writes)

__device__ __forceinline__ float wave_sum(float v) {
  #pragma unroll
  for (int off = 32; off; off >>= 1) v += __shfl_down(v, off);
  return v;
}
__device__ __forceinline__ float wave_max(float v) {
  #pragma unroll
  for (int off = 32; off; off >>= 1) v = fmaxf(v, __shfl_down(v, off));
  return v;
}

// ---- K1: mean over D per (b,c) row. One block per row. ----
__global__ void __launch_bounds__(256) k_mean(const float* __restrict__ x, float* __restrict__ mean) {
  int row = blockIdx.x;  // b*C + c
  const float4* xr = reinterpret_cast<const float4*>(x + (size_t)row * D);
  float s = 0.f;
  #pragma unroll
  for (int i = 0; i < 2; ++i) {
    float4 v = xr[threadIdx.x + i * 256];
    s += (v.x + v.y) + (v.z + v.w);
  }
  __shared__ float red[4];
  s = wave_sum(s);
  if ((threadIdx.x & 63) == 0) red[threadIdx.x >> 6] = s;
  __syncthreads();
  if (threadIdx.x == 0) mean[row] = (red[0] + red[1] + red[2] + red[3]) * (1.0f / D);
}

// ---- K2: q0 -> u[b,h,:] -> logit0[b,h]. One block per (b,h). ----
// (k-bias term is constant over l -> softmax-invariant -> dropped.)
__global__ void __launch_bounds__(256) k_qu(const float* __restrict__ wqkv,
                                            const float* __restrict__ bqkv,
                                            const float* __restrict__ pos,
                                            const float* __restrict__ mean,
                                            float* __restrict__ u,
                                            float* __restrict__ logit0) {
  int bh = blockIdx.x, b = bh >> 3, h = bh & 7;
  int tid = threadIdx.x, wid = tid >> 6, lane = tid & 63;
  __shared__ float mps[C];
  __shared__ float q0s[CH];
  __shared__ float us[C];
  __shared__ float red[4];
  for (int c = tid; c < C; c += 256) mps[c] = mean[b * C + c] + pos[(size_t)c * L];
  __syncthreads();
  for (int j = wid; j < CH; j += 4) {
    const float* wr = wqkv + (size_t)(h * CH + j) * C;
    float acc = 0.f;
    #pragma unroll
    for (int k = 0; k < 8; ++k) acc += wr[lane + k * 64] * mps[lane + k * 64];
    acc = wave_sum(acc);
    if (lane == 0) q0s[j] = acc + bqkv[h * CH + j];
  }
  __syncthreads();
  float a0 = 0.f, a1 = 0.f;
  #pragma unroll 4
  for (int j = 0; j < CH; ++j) {
    float qv = q0s[j];
    const float* wkr = wqkv + (size_t)(C + h * CH + j) * C;
    a0 += qv * wkr[tid];
    a1 += qv * wkr[tid + 256];
  }
  a0 *= 0.125f; a1 *= 0.125f;   // scale^2 = 1/sqrt(64)
  us[tid] = a0; us[tid + 256] = a1;
  u[(size_t)bh * C + tid] = a0;
  u[(size_t)bh * C + tid + 256] = a1;
  __syncthreads();
  float p = us[tid] * mps[tid] + us[tid + 256] * mps[tid + 256];
  p = wave_sum(p);
  if (lane == 0) red[wid] = p;
  __syncthreads();
  if (tid == 0) logit0[bh] = red[0] + red[1] + red[2] + red[3];
}

// ---- K3: fused logits + local softmax + xbar partials. ----
// grid (NLT, B), 512 thr. Phase A: wave<->64c chunk, lane<->l; u via SCALAR
// loads (readfirstlane-uniform address -> s_load, SGPR fma operand); x staged
// to LDS tile. Softmax: wave<->head, e stored TRANSPOSED e_t[l][8h]. Phase B:
// thread<->c, loop l; tile b32 + two broadcast b128 e reads per l.
__global__ void __launch_bounds__(512, 1) k_fused_lx(
    const float* __restrict__ x, const float* __restrict__ pos,
    const float* __restrict__ u_g,
    float* __restrict__ xpart, float* __restrict__ mpart, float* __restrict__ spart) {
  __shared__ float tile[64][TLD];     // 131328 B
  __shared__ float rlds[8][NH][64];   // 16384 B
  __shared__ float e_t[64][NH];       // 2048 B   (~149.8 KB total)
  int lt = blockIdx.x, b = blockIdx.y;
  int tid = threadIdx.x, wid = tid >> 6, lane = tid & 63;
  int cg = wid * 64;
  int col = lt * 64 + lane;           // x column; actual l = col+1

  // wave-uniform u base: readfirstlane makes the address provably scalar
  const float* ub = u_g + (size_t)b * NH * C + __builtin_amdgcn_readfirstlane(cg);

  float acc[NH];
  #pragma unroll
  for (int h = 0; h < NH; ++h) acc[h] = 0.f;

  const float* xp = x + ((size_t)(b * C + cg)) * D + col;
  const float* pp = pos + (size_t)cg * L + col + 1;
  #pragma unroll 4
  for (int cc = 0; cc < 64; ++cc) {
    float v = *xp + *pp;
    tile[lane][cg + cc] = v;
    xp += D; pp += L;
    #pragma unroll
    for (int h = 0; h < NH; ++h) acc[h] += ub[h * C + cc] * v;   // s_load + v_fmac(s)
  }
  #pragma unroll
  for (int h = 0; h < NH; ++h) rlds[wid][h][lane] = acc[h];
  __syncthreads();

  {  // wave wid finishes head h = wid: reduce over waves, local softmax
    int h = wid;
    float lg = 0.f;
    #pragma unroll
    for (int w = 0; w < 8; ++w) lg += rlds[w][h][lane];
    float m = wave_max(lg);
    m = __shfl(m, 0);
    float e = __expf(lg - m);
    float s = wave_sum(e);
    e_t[lane][h] = e;               // transposed: e_t[l][h]
    if (lane == 0) {
      mpart[(b * NH + h) * NLT + lt] = m;
      spart[(b * NH + h) * NLT + lt] = s;
    }
  }
  __syncthreads();

  // Phase B: thread <-> c; per l: 1 b32 tile read + 2 broadcast b128 e reads
  float a2[NH];
  #pragma unroll
  for (int h = 0; h < NH; ++h) a2[h] = 0.f;
  #pragma unroll 8
  for (int l = 0; l < 64; ++l) {
    float xv = tile[l][tid];
    float4 e0 = *reinterpret_cast<const float4*>(&e_t[l][0]);
    float4 e1 = *reinterpret_cast<const float4*>(&e_t[l][4]);
    a2[0] += e0.x * xv; a2[1] += e0.y * xv; a2[2] += e0.z * xv; a2[3] += e0.w * xv;
    a2[4] += e1.x * xv; a2[5] += e1.y * xv; a2[6] += e1.z * xv; a2[7] += e1.w * xv;
  }
  #pragma unroll
  for (int h = 0; h < NH; ++h)
    xpart[(((size_t)b * NLT + lt) * NH + h) * C + tid] = a2[h];
}

// ---- K4: combine 32 tile-partials (rescale by global max) + l=0 term,
//          normalize -> xbar row, then a0 slice for this head. Block = (b,h). ----
__global__ void __launch_bounds__(512) k_comb_a0(
    const float* __restrict__ xpart, const float* __restrict__ mpart,
    const float* __restrict__ spart, const float* __restrict__ logit0,
    const float* __restrict__ mean, const float* __restrict__ pos,
    const float* __restrict__ wqkv, const float* __restrict__ bqkv,
    float* __restrict__ a0v) {
  int bh = blockIdx.x, b = bh >> 3, h = bh & 7;
  int tid = threadIdx.x, wid = tid >> 6, lane = tid & 63;
  __shared__ float row[C];
  __shared__ float rr[NLT];
  __shared__ float Msh, Sinv;
  float lg0 = logit0[bh];
  if (tid < NLT) rr[tid] = mpart[bh * NLT + tid];
  __syncthreads();
  if (tid == 0) {
    float M = lg0;
    #pragma unroll
    for (int t = 0; t < NLT; ++t) M = fmaxf(M, rr[t]);
    Msh = M;
  }
  __syncthreads();
  float M = Msh;
  if (tid < NLT) rr[tid] = __expf(rr[tid] - M);
  __syncthreads();
  if (tid == 0) {
    float S = __expf(lg0 - M);
    #pragma unroll
    for (int t = 0; t < NLT; ++t) S += spart[bh * NLT + t] * rr[t];
    Sinv = 1.0f / S;
  }
  float acc = 0.f;
  #pragma unroll 4
  for (int t = 0; t < NLT; ++t)
    acc += xpart[(((size_t)b * NLT + t) * NH + h) * C + tid] * rr[t];
  float xf0 = mean[b * C + tid] + pos[(size_t)tid * L];
  acc += __expf(lg0 - M) * xf0;
  __syncthreads();               // Sinv ready
  row[tid] = acc * Sinv;
  __syncthreads();
  // a0[b, h*64+j] = W_v[h*64+j,:] . row + b_v
  #pragma unroll 2
  for (int j = 0; j < 8; ++j) {
    int o = h * CH + wid * 8 + j;
    const float* wr = wqkv + (size_t)(2 * C + o) * C;
    float d = 0.f;
    #pragma unroll
    for (int k = 0; k < 8; ++k) d += wr[lane + k * 64] * row[lane + k * 64];
    d = wave_sum(d);
    if (lane == 0) a0v[b * C + o] = d + bqkv[2 * C + o];
  }
}

// ---- K5: out[b,o] = W_c[o,:] . a0[b,:] + b_c[o]. Block = (b, 64-o chunk). ----
__global__ void __launch_bounds__(512) k_out(const float* __restrict__ wc,
                                             const float* __restrict__ bc,
                                             const float* __restrict__ a0v,
                                             float* __restrict__ out) {
  int bid = blockIdx.x, b = bid >> 3, og = (bid & 7) * 64;
  int tid = threadIdx.x, wid = tid >> 6, lane = tid & 63;
  __shared__ float row[C];
  row[tid] = a0v[b * C + tid];
  __syncthreads();
  #pragma unroll 2
  for (int j = 0; j < 8; ++j) {
    int o = og + wid * 8 + j;
    const float* wr = wc + (size_t)o * C;
    float d = 0.f;
    #pragma unroll
    for (int k = 0; k < 8; ++k) d += wr[lane + k * 64] * row[lane + k * 64];
    d = wave_sum(d);
    if (lane == 0) out[b * C + o] = d + bc[o];
  }
}

extern "C" void kernel_launch(void* const* d_in, const int* in_sizes, int n_in,
                              void* d_out, int out_size, void* d_ws, size_t ws_size,
                              hipStream_t stream) {
  const float* x    = (const float*)d_in[0];
  const float* pos  = (const float*)d_in[1];
  const float* wqkv = (const float*)d_in[2];
  const float* bqkv = (const float*)d_in[3];
  const float* wc   = (const float*)d_in[4];
  const float* bc   = (const float*)d_in[5];
  float* out = (float*)d_out;
  float* ws  = (float*)d_ws;

  float* mean   = ws;               // 4096
  float* u      = ws + 4096;        // 32768
  float* logit0 = ws + 36864;       // 64
  float* mpart  = ws + 36928;       // 2048
  float* spart  = ws + 38976;       // 2048
  float* a0v    = ws + 41024;       // 4096
  float* xpart  = ws + 45120;       // 8*32*8*512 = 1048576  (total ~4.4 MB)

  hipLaunchKernelGGL(k_mean,     dim3(B * C),    dim3(256), 0, stream, x, mean);
  hipLaunchKernelGGL(k_qu,       dim3(B * NH),   dim3(256), 0, stream, wqkv, bqkv, pos, mean, u, logit0);
  hipLaunchKernelGGL(k_fused_lx, dim3(NLT, B),   dim3(512), 0, stream, x, pos, u, xpart, mpart, spart);
  hipLaunchKernelGGL(k_comb_a0,  dim3(B * NH),   dim3(512), 0, stream, xpart, mpart, spart, logit0,
                     mean, pos, wqkv, bqkv, a0v);
  hipLaunchKernelGGL(k_out,      dim3(B * NH),   dim3(512), 0, stream, wc, bc, a0v, out);
}

// Round 6
// 56.025 us; speedup vs baseline: 4.8056x; 1.0369x over previous
//
#include <hip/hip_runtime.h>

#define B 8
#define C 512
#define D 2048     // spatial positions
#define L 2049     // D+1
#define NH 8
#define CH 64
#define NLT 32     // l-tiles of 64 in the fused pass
#define TLD 513    // LDS tile leading dim (odd stride -> conflict-free)

__device__ __forceinline__ float wave_sum(float v) {
  #pragma unroll
  for (int off = 32; off; off >>= 1) v += __shfl_down(v, off);
  return v;
}
__device__ __forceinline__ float wave_max(float v) {
  #pragma unroll
  for (int off = 32; off; off >>= 1) v = fmaxf(v, __shfl_down(v, off));
  return v;
}
// wave-uniform broadcast via v_readlane (SGPR result, no DS-pipe traffic).
// l must be compile-time constant (use inside fully-unrolled loops).
__device__ __forceinline__ float lane_bcast(float v, int l) {
  return __uint_as_float(__builtin_amdgcn_readlane(__float_as_uint(v), l));
}

// ---- K1: mean over D per (b,c) row. One block per row. ----
__global__ void __launch_bounds__(256) k_mean(const float* __restrict__ x, float* __restrict__ mean) {
  int row = blockIdx.x;  // b*C + c
  const float4* xr = reinterpret_cast<const float4*>(x + (size_t)row * D);
  float s = 0.f;
  #pragma unroll
  for (int i = 0; i < 2; ++i) {
    float4 v = xr[threadIdx.x + i * 256];
    s += (v.x + v.y) + (v.z + v.w);
  }
  __shared__ float red[4];
  s = wave_sum(s);
  if ((threadIdx.x & 63) == 0) red[threadIdx.x >> 6] = s;
  __syncthreads();
  if (threadIdx.x == 0) mean[row] = (red[0] + red[1] + red[2] + red[3]) * (1.0f / D);
}

// ---- K2: q0 -> u[b,h,:] -> logit0[b,h]; h==0 blocks also persist
//      mps[b,c] = mean+pos0 (coalesced for the tail kernels). ----
__global__ void __launch_bounds__(256) k_qu(const float* __restrict__ wqkv,
                                            const float* __restrict__ bqkv,
                                            const float* __restrict__ pos,
                                            const float* __restrict__ mean,
                                            float* __restrict__ u,
                                            float* __restrict__ logit0,
                                            float* __restrict__ mps_g) {
  int bh = blockIdx.x, b = bh >> 3, h = bh & 7;
  int tid = threadIdx.x, wid = tid >> 6, lane = tid & 63;
  __shared__ float mps[C];
  __shared__ float q0s[CH];
  __shared__ float us[C];
  __shared__ float red[4];
  for (int c = tid; c < C; c += 256) {
    float v = mean[b * C + c] + pos[(size_t)c * L];
    mps[c] = v;
    if (h == 0) mps_g[b * C + c] = v;
  }
  __syncthreads();
  for (int j = wid; j < CH; j += 4) {
    const float* wr = wqkv + (size_t)(h * CH + j) * C;
    float acc = 0.f;
    #pragma unroll
    for (int k = 0; k < 8; ++k) acc += wr[lane + k * 64] * mps[lane + k * 64];
    acc = wave_sum(acc);
    if (lane == 0) q0s[j] = acc + bqkv[h * CH + j];
  }
  __syncthreads();
  float a0 = 0.f, a1 = 0.f;
  #pragma unroll 4
  for (int j = 0; j < CH; ++j) {
    float qv = q0s[j];
    const float* wkr = wqkv + (size_t)(C + h * CH + j) * C;
    a0 += qv * wkr[tid];
    a1 += qv * wkr[tid + 256];
  }
  a0 *= 0.125f; a1 *= 0.125f;   // scale^2 = 1/sqrt(64)
  us[tid] = a0; us[tid + 256] = a1;
  u[(size_t)bh * C + tid] = a0;
  u[(size_t)bh * C + tid + 256] = a1;
  __syncthreads();
  float p = us[tid] * mps[tid] + us[tid + 256] * mps[tid + 256];
  p = wave_sum(p);
  if (lane == 0) red[wid] = p;
  __syncthreads();
  if (tid == 0) logit0[bh] = red[0] + red[1] + red[2] + red[3];
}

// ---- K3: fused logits + local softmax + xbar partials. grid (NLT, B), 512 thr.
// Phase A: wave<->64c chunk, lane<->l; u in VGPRs, broadcast via v_readlane
// (fully-unrolled loop -> compile-time lane idx -> SGPR fmac operand).
// Phase B: thread<->c, e pre-loaded to 8 VGPRs, broadcast via v_readlane. ----
__global__ void __launch_bounds__(512, 1) k_fused_lx(
    const float* __restrict__ x, const float* __restrict__ pos,
    const float* __restrict__ u_g,
    float* __restrict__ xpart, float* __restrict__ mpart, float* __restrict__ spart) {
  __shared__ float tile[64][TLD];     // 131328 B
  __shared__ float rlds[8][NH][64];   // 16384 B
  __shared__ float e_t[64][9];        // 2304 B (pad 9: conflict-free both ways)
  int lt = blockIdx.x, b = blockIdx.y;
  int tid = threadIdx.x, wid = tid >> 6, lane = tid & 63;
  int cg = wid * 64;
  int col = lt * 64 + lane;           // x column; actual l = col+1

  float ureg[NH];
  #pragma unroll
  for (int h = 0; h < NH; ++h) ureg[h] = u_g[(size_t)(b * NH + h) * C + cg + lane];

  float acc[NH];
  #pragma unroll
  for (int h = 0; h < NH; ++h) acc[h] = 0.f;

  const float* xp = x + ((size_t)(b * C + cg)) * D + col;
  const float* pp = pos + (size_t)cg * L + col + 1;
  #pragma unroll
  for (int cc = 0; cc < 64; ++cc) {
    float v = xp[(size_t)cc * D] + pp[(size_t)cc * L];
    tile[lane][cg + cc] = v;
    #pragma unroll
    for (int h = 0; h < NH; ++h) acc[h] += lane_bcast(ureg[h], cc) * v;
  }
  #pragma unroll
  for (int h = 0; h < NH; ++h) rlds[wid][h][lane] = acc[h];
  __syncthreads();

  {  // wave wid finishes head h = wid: reduce over waves, local softmax
    int h = wid;
    float lg = 0.f;
    #pragma unroll
    for (int w = 0; w < 8; ++w) lg += rlds[w][h][lane];
    float m = wave_max(lg);
    m = lane_bcast(m, 0);
    float e = __expf(lg - m);
    float s = wave_sum(e);
    e_t[lane][h] = e;               // transposed: e_t[l][h]
    if (lane == 0) {
      mpart[(b * NH + h) * NLT + lt] = m;
      spart[(b * NH + h) * NLT + lt] = s;
    }
  }
  __syncthreads();

  // Phase B: thread <-> c; e via registers + readlane, tile b32 reads only.
  float epre[NH];
  #pragma unroll
  for (int h = 0; h < NH; ++h) epre[h] = e_t[lane][h];
  float a2[NH];
  #pragma unroll
  for (int h = 0; h < NH; ++h) a2[h] = 0.f;
  #pragma unroll
  for (int l = 0; l < 64; ++l) {
    float xv = tile[l][tid];
    #pragma unroll
    for (int h = 0; h < NH; ++h) a2[h] += lane_bcast(epre[h], l) * xv;
  }
  #pragma unroll
  for (int h = 0; h < NH; ++h)
    xpart[(((size_t)b * NLT + lt) * NH + h) * C + tid] = a2[h];
}

// ---- K4: combine 32 tile-partials + l=0 term, normalize -> xbar row (LDS),
//          then a0 slice for this head. Block = (b,h). ----
__global__ void __launch_bounds__(512) k_a0(
    const float* __restrict__ xpart, const float* __restrict__ mpart,
    const float* __restrict__ spart, const float* __restrict__ logit0,
    const float* __restrict__ mps_g,
    const float* __restrict__ wqkv, const float* __restrict__ bqkv,
    float* __restrict__ a0v) {
  int bh = blockIdx.x, b = bh >> 3, h = bh & 7;
  int tid = threadIdx.x, wid = tid >> 6, lane = tid & 63;
  __shared__ float row[C];
  float lg0 = logit0[bh];
  // per-wave (redundant) combine factors in lane registers
  float mt = (lane < NLT) ? mpart[bh * NLT + lane] : -3.0e38f;
  float M = fmaxf(lane_bcast(wave_max(mt), 0), lg0);
  float rr = (lane < NLT) ? __expf(mt - M) : 0.f;
  float st = (lane < NLT) ? spart[bh * NLT + lane] * rr : 0.f;
  float S = lane_bcast(wave_sum(st), 0) + __expf(lg0 - M);
  float Sinv = 1.0f / S;
  // xbar[c=tid]
  float acc = 0.f;
  #pragma unroll
  for (int t = 0; t < NLT; ++t)
    acc += xpart[(((size_t)b * NLT + t) * NH + h) * C + tid] * lane_bcast(rr, t);
  acc = (acc + __expf(lg0 - M) * mps_g[b * C + tid]) * Sinv;
  row[tid] = acc;
  __syncthreads();
  // a0[b, h*64+j]: xbar row cached in 8 regs, wave wid handles 8 outputs
  float xr[8];
  #pragma unroll
  for (int k = 0; k < 8; ++k) xr[k] = row[k * 64 + lane];
  #pragma unroll 2
  for (int j = 0; j < 8; ++j) {
    int o = h * CH + wid * 8 + j;
    const float* wr = wqkv + (size_t)(2 * C + o) * C;
    float d = 0.f;
    #pragma unroll
    for (int k = 0; k < 8; ++k) d += wr[k * 64 + lane] * xr[k];
    d = wave_sum(d);
    if (lane == 0) a0v[b * C + o] = d + bqkv[2 * C + o];
  }
}

// ---- K5: out[b,o] = W_c[o,:] . a0[b,:] + b_c[o]. Block = (b, 64-o chunk). ----
__global__ void __launch_bounds__(512) k_out(const float* __restrict__ wc,
                                             const float* __restrict__ bc,
                                             const float* __restrict__ a0v,
                                             float* __restrict__ out) {
  int bid = blockIdx.x, b = bid >> 3, og = (bid & 7) * 64;
  int tid = threadIdx.x, wid = tid >> 6, lane = tid & 63;
  __shared__ float row[C];
  row[tid] = a0v[b * C + tid];
  __syncthreads();
  float xr[8];
  #pragma unroll
  for (int k = 0; k < 8; ++k) xr[k] = row[k * 64 + lane];
  #pragma unroll 2
  for (int j = 0; j < 8; ++j) {
    int o = og + wid * 8 + j;
    const float* wr = wc + (size_t)o * C;
    float d = 0.f;
    #pragma unroll
    for (int k = 0; k < 8; ++k) d += wr[k * 64 + lane] * xr[k];
    d = wave_sum(d);
    if (lane == 0) out[b * C + o] = d + bc[o];
  }
}

extern "C" void kernel_launch(void* const* d_in, const int* in_sizes, int n_in,
                              void* d_out, int out_size, void* d_ws, size_t ws_size,
                              hipStream_t stream) {
  const float* x    = (const float*)d_in[0];
  const float* pos  = (const float*)d_in[1];
  const float* wqkv = (const float*)d_in[2];
  const float* bqkv = (const float*)d_in[3];
  const float* wc   = (const float*)d_in[4];
  const float* bc   = (const float*)d_in[5];
  float* out = (float*)d_out;
  float* ws  = (float*)d_ws;

  float* mean   = ws;               // 4096
  float* u      = ws + 4096;        // 32768
  float* logit0 = ws + 36864;       // 64
  float* mpart  = ws + 36928;       // 2048
  float* spart  = ws + 38976;       // 2048
  float* a0v    = ws + 41024;       // 4096
  float* mps_g  = ws + 45120;       // 4096
  float* xpart  = ws + 49216;       // 8*32*8*512 = 1048576  (total ~4.4 MB)

  hipLaunchKernelGGL(k_mean,     dim3(B * C),    dim3(256), 0, stream, x, mean);
  hipLaunchKernelGGL(k_qu,       dim3(B * NH),   dim3(256), 0, stream, wqkv, bqkv, pos, mean, u, logit0, mps_g);
  hipLaunchKernelGGL(k_fused_lx, dim3(NLT, B),   dim3(512), 0, stream, x, pos, u, xpart, mpart, spart);
  hipLaunchKernelGGL(k_a0,       dim3(B * NH),   dim3(512), 0, stream, xpart, mpart, spart, logit0,
                     mps_g, wqkv, bqkv, a0v);
  hipLaunchKernelGGL(k_out,      dim3(B * NH),   dim3(512), 0, stream, wc, bc, a0v, out);
}